// Round 9
// baseline (627.184 us; speedup 1.0000x reference)
//
#include <hip/hip_runtime.h>
#include <hip/hip_bf16.h>

// ---- problem constants ----
#define N_NODES   100000
#define N_EDGES   1600000
#define N_MEMB    150000
#define N_CLUST   40000
#define N_EDGESP  800000
#define NB        64
#define NCLS      10
#define NETOT     2550000        // E + M + E2

typedef __attribute__((ext_vector_type(4))) float f32x4;
typedef __attribute__((ext_vector_type(8))) short bf16x8;

// ---- workspace layout (byte offsets) ----
#define OFF_A0   0ul            // bf16 activation arena 0 (100000x128)
#define OFF_A1   25600000ul     // arena 1
#define OFF_A2   51200000ul     // arena 2
#define OFF_XB   76800000ul     // converted-input arena (bf16)
#define OFF_WP   102400000ul    // packed weights: 6 x 65536 B
#define OFF_WB   102793216ul    // converted biases + head weights (bf16)
#define OFF_IB   102801408ul    // int region (16B aligned)
// int region offsets (ints)
#define I_PART  0               // packed edge partition buffer (uint x 2.55M)
#define I_COL   2560000         // unified col array (2.55M)
#define I_NRP   5110016         // node rowptr 100001
#define I_MRP   5210032         // memb rowptr 40001
#define I_CRP   5250048         // cluster rowptr 40001
#define I_BCNT  5290064         // 544
#define I_PST   5290608         // 545
#define I_BCUR  5291168         // 544
#define I_FLAG  5291712
// end ~5.29M ints => total ws ~124 MB (harness provides >=165 MB, proven round 2)

#define PART_BLOCK 4096         // virtual edges per partition block (512 thr x 8)
#define SG_SHIFT   14
// partition geometry: node nbuck=49 ng=7 -> [0,343); memb nbuck=20 ng=7 ->
// [343,483); cluster nbuck=20 ng=3 -> [483,543)
#define PB_N   0
#define PB_M   343
#define PB_C   483
#define NPART  543
#define NBK_N  49
#define NBK_M  20
#define NBK_C  20

__device__ __forceinline__ unsigned short f2bf(float f) {   // RNE round
  unsigned u = __float_as_uint(f);
  return (unsigned short)((u + 0x7FFFu + ((u >> 16) & 1u)) >> 16);
}
__device__ __forceinline__ float bflo(unsigned u) { return __uint_as_float(u << 16); }
__device__ __forceinline__ float bfhi(unsigned u) { return __uint_as_float(u & 0xFFFF0000u); }

// Detect whether "float" inputs are bf16 (flag=1) or f32 (flag=0).
__global__ void probe_dtype(const unsigned short* __restrict__ x, int* __restrict__ flag) {
  if (blockIdx.x != 0 || threadIdx.x != 0) return;
  int wild = 0;
  for (int i = 0; i < 1024; i += 2) {
    int e = (x[i] >> 7) & 0xFF;
    if (e > 0x85) wild++;
  }
  *flag = (wild < 8) ? 1 : 0;
}

// ============ merged ingestion: x conversion + weight packs + biases ============
struct PackArgs {
  const void* wl[6];
  const void* wr[6];
  int         wrOff[6];
  const void* bb[6];
  const void* w2;
  const void* b2;
};

__global__ __launch_bounds__(256) void ingest_all(
    const void* __restrict__ x, uint4* __restrict__ xB,
    PackArgs pa, uint4* __restrict__ wp, unsigned short* __restrict__ wb,
    const int* __restrict__ flag) {
  int isb = *flag;
  int bid = blockIdx.x;
  if (bid < 6250) {                            // cvt_x: 8 elems/thread
    int gid = bid * 256 + threadIdx.x;
    if (gid >= 1600000) return;
    if (isb) {
      xB[gid] = ((const uint4*)x)[gid];
    } else {
      const float4* xf = (const float4*)x;
      float4 a = xf[2 * gid], b = xf[2 * gid + 1];
      unsigned short v[8] __attribute__((aligned(16)));
      v[0] = f2bf(a.x); v[1] = f2bf(a.y); v[2] = f2bf(a.z); v[3] = f2bf(a.w);
      v[4] = f2bf(b.x); v[5] = f2bf(b.y); v[6] = f2bf(b.z); v[7] = f2bf(b.w);
      xB[gid] = *(const uint4*)v;
    }
  } else if (bid < 6346) {                     // weight pack, MFMA A-frag order
    int pb = bid - 6250;                       // 0..95
    int L = pb >> 4;
    const void* Wlv = pa.wl[L];
    const void* Wrv = pa.wr[L];
    int wrOff = pa.wrOff[L];
    int t = (pb & 15) * 256 + threadIdx.x;     // 0..4095
    int lane = t & 63, mt = (t >> 6) & 7, ks = t >> 9;
    int feat = mt * 16 + (lane & 15);
    int k0 = ks * 32 + (lane >> 4) * 8;
    unsigned short v[8] __attribute__((aligned(16)));
#pragma unroll
    for (int j = 0; j < 8; ++j) {
      int k = k0 + j;
      int idx = ((k < 128) ? k * 128 : (k - 128) * 128 + wrOff) + feat;
      const void* W = (k < 128) ? Wlv : Wrv;
      v[j] = isb ? ((const unsigned short*)W)[idx] : f2bf(((const float*)W)[idx]);
    }
    wp[L * 4096 + t] = *(const uint4*)v;
  } else {                                     // biases + head weights
    for (int gid = threadIdx.x; gid < 2058; gid += 256) {
      const void* src; int local;
      if (gid < 768) { int seg = gid >> 7; local = gid & 127; src = pa.bb[seg]; }
      else if (gid < 2048) { src = pa.w2; local = gid - 768; }
      else { src = pa.b2; local = gid - 2048; }
      wb[gid] = isb ? ((const unsigned short*)src)[local] : f2bf(((const float*)src)[local]);
    }
  }
}

// ============ fused binned CSR build over all 3 graphs ============
// virtual edge i: [0,E) node; [E,E+M) memb; [E+M,NETOT) cluster.
__device__ __forceinline__ void vedge(int i,
    const int* __restrict__ s1, const int* __restrict__ d1,
    const int* __restrict__ s2, const int* __restrict__ d2,
    const int* __restrict__ s3, const int* __restrict__ d3,
    int& s, int& d, int& pk) {
  if (i < N_EDGES)               { s = s1[i]; d = d1[i]; pk = PB_N + (d >> 11) * 7 + (s >> SG_SHIFT); }
  else if (i < N_EDGES + N_MEMB) { int j = i - N_EDGES; s = s2[j]; d = d2[j]; pk = PB_M + (d >> 11) * 7 + (s >> SG_SHIFT); }
  else                           { int j = i - N_EDGES - N_MEMB; s = s3[j]; d = d3[j]; pk = PB_C + (d >> 11) * 3 + (s >> SG_SHIFT); }
}

__global__ __launch_bounds__(512) void bucket_count_all(
    const int* __restrict__ s1, const int* __restrict__ d1,
    const int* __restrict__ s2, const int* __restrict__ d2,
    const int* __restrict__ s3, const int* __restrict__ d3,
    int* __restrict__ bcnt) {
  __shared__ int h[544];
  int tid = threadIdx.x;
  h[tid] = 0;
  if (tid < 32) h[512 + tid] = 0;
  __syncthreads();
  int base = blockIdx.x * PART_BLOCK + tid;
#pragma unroll
  for (int j = 0; j < 8; ++j) {
    int i = base + j * 512;
    if (i < NETOT) { int s, d, pk; vedge(i, s1, d1, s2, d2, s3, d3, s, d, pk); atomicAdd(&h[pk], 1); }
  }
  __syncthreads();
  if (h[tid]) atomicAdd(&bcnt[tid], h[tid]);
  if (tid < 31 && h[512 + tid]) atomicAdd(&bcnt[512 + tid], h[512 + tid]);
}

// exclusive scan of bcnt[0..NPART) -> pstart[0..NPART], bcur = pstart
__global__ __launch_bounds__(512) void scan_all(const int* __restrict__ bcnt,
                                                int* __restrict__ pstart,
                                                int* __restrict__ bcur) {
  __shared__ int ws[8];
  int tid = threadIdx.x, lane = tid & 63, wv = tid >> 6;
  int v0 = (2 * tid < NPART) ? bcnt[2 * tid] : 0;
  int v1 = (2 * tid + 1 < NPART) ? bcnt[2 * tid + 1] : 0;
  int s = v0 + v1;
  int inc = s;
  for (int off = 1; off < 64; off <<= 1) {
    int u = __shfl_up(inc, off);
    if (lane >= off) inc += u;
  }
  if (lane == 63) ws[wv] = inc;
  __syncthreads();
  int woff = 0;
  for (int k = 0; k < wv; ++k) woff += ws[k];
  int e0 = woff + inc - s;
  if (2 * tid < NPART)     { pstart[2 * tid] = e0;          bcur[2 * tid] = e0; }
  if (2 * tid + 1 < NPART) { pstart[2 * tid + 1] = e0 + v0; bcur[2 * tid + 1] = e0 + v0; }
  if (tid == 0) {
    int t = 0;
    for (int k = 0; k < 8; ++k) t += ws[k];
    pstart[NPART] = t;
  }
}

__global__ __launch_bounds__(512) void partition_all(
    const int* __restrict__ s1, const int* __restrict__ d1,
    const int* __restrict__ s2, const int* __restrict__ d2,
    const int* __restrict__ s3, const int* __restrict__ d3,
    int* __restrict__ bcur, unsigned* __restrict__ part) {
  __shared__ int h[544], lcur[544];
  int tid = threadIdx.x;
  h[tid] = 0;
  if (tid < 32) h[512 + tid] = 0;
  __syncthreads();
  int base = blockIdx.x * PART_BLOCK + tid;
  int s[8], d[8], bk[8];
#pragma unroll
  for (int j = 0; j < 8; ++j) {
    int i = base + j * 512;
    if (i < NETOT) { vedge(i, s1, d1, s2, d2, s3, d3, s[j], d[j], bk[j]); atomicAdd(&h[bk[j]], 1); }
    else bk[j] = -1;
  }
  __syncthreads();
  if (h[tid]) lcur[tid] = atomicAdd(&bcur[tid], h[tid]);
  if (tid < 31 && h[512 + tid]) lcur[512 + tid] = atomicAdd(&bcur[512 + tid], h[512 + tid]);
  __syncthreads();
#pragma unroll
  for (int j = 0; j < 8; ++j) {
    if (bk[j] >= 0) {
      int p = atomicAdd(&lcur[bk[j]], 1);
      part[p] = (unsigned)s[j] | ((unsigned)(d[j] & 2047) << 17);
    }
  }
}

// one workgroup per (graph,bucket): LDS histogram -> scan -> rowptr, then
// group-sequential scatter of col into the unified col array.
__global__ __launch_bounds__(1024) void binned_fill_all(
    const unsigned* __restrict__ part, const int* __restrict__ pstart,
    int* __restrict__ nrp, int* __restrict__ mrp, int* __restrict__ crp,
    int* __restrict__ col) {
  __shared__ int cnt[2048];
  __shared__ int wsum[16];
  int b = blockIdx.x, tid = threadIdx.x;
  int buck, pb, ng, n;
  int* rp;
  if (b < NBK_N)               { buck = b;           pb = PB_N + buck * 7; ng = 7; rp = nrp; n = N_NODES; }
  else if (b < NBK_N + NBK_M)  { buck = b - NBK_N;   pb = PB_M + buck * 7; ng = 7; rp = mrp; n = N_CLUST; }
  else                         { buck = b - NBK_N - NBK_M; pb = PB_C + buck * 3; ng = 3; rp = crp; n = N_CLUST; }
  int nbase = buck << 11;
  int nn = n - nbase; if (nn > 2048) nn = 2048;
  cnt[tid] = 0; cnt[tid + 1024] = 0;
  __syncthreads();
  int e0 = pstart[pb], e1 = pstart[pb + ng];
  for (int e = e0 + tid; e < e1; e += 1024)
    atomicAdd(&cnt[part[e] >> 17], 1);
  __syncthreads();
  int c0 = cnt[2 * tid], c1 = cnt[2 * tid + 1];
  int s = c0 + c1;
  int lane = tid & 63, wv = tid >> 6;
  int inc = s;
  for (int off = 1; off < 64; off <<= 1) {
    int u = __shfl_up(inc, off);
    if (lane >= off) inc += u;
  }
  if (lane == 63) wsum[wv] = inc;
  __syncthreads();
  int woff = 0;
  for (int k = 0; k < wv; ++k) woff += wsum[k];
  int excl = woff + (inc - s);
  int r0 = e0 + excl;
  int r1 = r0 + c0;
  __syncthreads();
  cnt[2 * tid] = r0; cnt[2 * tid + 1] = r1;
  if (2 * tid < nn)     rp[nbase + 2 * tid]     = r0;
  if (2 * tid + 1 < nn) rp[nbase + 2 * tid + 1] = r1;
  __syncthreads();
  for (int g = 0; g < ng; ++g) {
    int f0 = pstart[pb + g], f1 = pstart[pb + g + 1];
    for (int e = f0 + tid; e < f1; e += 1024) {
      unsigned ed = part[e];
      int p = atomicAdd(&cnt[ed >> 17], 1);
      col[p] = (int)(ed & 0x1FFFFu);
    }
    __syncthreads();
  }
  if (tid == 0) {
    if (b == NBK_N - 1)                 nrp[N_NODES] = pstart[PB_M];
    if (b == NBK_N + NBK_M - 1)         mrp[N_CLUST] = pstart[PB_C];
    if (b == NBK_N + NBK_M + NBK_C - 1) crp[N_CLUST] = pstart[NPART];
  }
}

// ============ standalone pull-mean (memb pool), bf16 rows ============
__global__ __launch_bounds__(256) void gather_mean_bf16(
    const uint2* __restrict__ x, const int* __restrict__ rowptr, const int* __restrict__ col,
    uint2* __restrict__ out, int n) {
  int w = (blockIdx.x * 256 + threadIdx.x) >> 6;
  if (w >= n) return;
  int lane = threadIdx.x & 63;
  int half = lane >> 5, p = lane & 31;
  int s0 = rowptr[w], s1 = rowptr[w + 1];
  float a0 = 0.f, a1 = 0.f, a2 = 0.f, a3 = 0.f;
  int j = s0 + half;
  for (; j + 14 < s1; j += 16) {
    uint2 v[8];
#pragma unroll
    for (int u = 0; u < 8; ++u) v[u] = x[((size_t)col[j + 2 * u] << 5) + p];
#pragma unroll
    for (int u = 0; u < 8; ++u) {
      a0 += bflo(v[u].x); a1 += bfhi(v[u].x);
      a2 += bflo(v[u].y); a3 += bfhi(v[u].y);
    }
  }
  for (; j < s1; j += 2) {
    uint2 v = x[((size_t)col[j] << 5) + p];
    a0 += bflo(v.x); a1 += bfhi(v.x);
    a2 += bflo(v.y); a3 += bfhi(v.y);
  }
  a0 += __shfl_xor(a0, 32); a1 += __shfl_xor(a1, 32);
  a2 += __shfl_xor(a2, 32); a3 += __shfl_xor(a3, 32);
  if (half == 0) {
    float sc = (s1 > s0) ? 1.0f / (float)(s1 - s0) : 0.f;
    uint2 r;
    r.x = (unsigned)f2bf(a0 * sc) | ((unsigned)f2bf(a1 * sc) << 16);
    r.y = (unsigned)f2bf(a2 * sc) | ((unsigned)f2bf(a3 * sc) << 16);
    out[((size_t)w << 5) + p] = r;
  }
}

// ============ fused gather + MFMA conv ============
// out = relu([mean_nbr(S) | S] @ [Wl;Wr] + b). 64 rows/block, 4 waves.
// Wave w gathers rows 16w..16w+15 (half-wave per edge), packs bf16 means
// straight into the swizzled LDS A-region; X-region staged from S rows.
__global__ __launch_bounds__(256) void gconv_mfma(
    const unsigned short* __restrict__ S,
    const int* __restrict__ rowptr, const int* __restrict__ col,
    const uint4* __restrict__ Wp, const unsigned short* __restrict__ bias,
    unsigned short* __restrict__ out, int nrows) {
  __shared__ uint4 lds[2048];                  // 32 KB: A segs 0-15, X segs 16-31
  int tid = threadIdx.x;
  int row0 = blockIdx.x * 64;

  // stage X half (own rows, contiguous)
  const char* Sb = (const char*)S;
  for (int c = tid; c < 1024; c += 256) {
    int r = c >> 4, sg = c & 15;
    int gr = row0 + r;
    uint4 v = make_uint4(0u, 0u, 0u, 0u);
    if (gr < nrows) v = *(const uint4*)(Sb + (size_t)gr * 256 + sg * 16);
    int byteoff = (r << 9) + ((((16 + sg) << 4)) ^ ((r & 7) << 4));
    *(uint4*)((char*)lds + byteoff) = v;
  }

  // gather phase: A region
  int lane = tid & 63, w = tid >> 6;
  int half = lane >> 5, p = lane & 31;
  const uint2* xs = (const uint2*)S;
  for (int i = 0; i < 16; ++i) {
    int r = 16 * w + i;
    int gr = row0 + r;
    int s0 = 0, s1 = 0;
    if (gr < nrows) { s0 = rowptr[gr]; s1 = rowptr[gr + 1]; }
    float a0 = 0.f, a1 = 0.f, a2 = 0.f, a3 = 0.f;
    int j = s0 + half;
    for (; j + 14 < s1; j += 16) {
      uint2 v[8];
#pragma unroll
      for (int u = 0; u < 8; ++u) v[u] = xs[((size_t)col[j + 2 * u] << 5) + p];
#pragma unroll
      for (int u = 0; u < 8; ++u) {
        a0 += bflo(v[u].x); a1 += bfhi(v[u].x);
        a2 += bflo(v[u].y); a3 += bfhi(v[u].y);
      }
    }
    for (; j < s1; j += 2) {
      uint2 v = xs[((size_t)col[j] << 5) + p];
      a0 += bflo(v.x); a1 += bfhi(v.x);
      a2 += bflo(v.y); a3 += bfhi(v.y);
    }
    a0 += __shfl_xor(a0, 32); a1 += __shfl_xor(a1, 32);
    a2 += __shfl_xor(a2, 32); a3 += __shfl_xor(a3, 32);
    if (half == 0) {
      float sc = (s1 > s0) ? 1.0f / (float)(s1 - s0) : 0.f;
      uint2 rv;
      rv.x = (unsigned)f2bf(a0 * sc) | ((unsigned)f2bf(a1 * sc) << 16);
      rv.y = (unsigned)f2bf(a2 * sc) | ((unsigned)f2bf(a3 * sc) << 16);
      int byteoff = (r << 9) + ((((p >> 1) << 4)) ^ ((r & 7) << 4)) + ((p & 1) << 3);
      *(uint2*)((char*)lds + byteoff) = rv;
    }
  }
  __syncthreads();

  // conv phase (identical to conv_mfma)
  int brow = 16 * w + (lane & 15);
  int q = lane >> 4;
  int q16 = q << 4;

  f32x4 acc[8];
#pragma unroll
  for (int mt = 0; mt < 8; ++mt) acc[mt] = (f32x4){0.f, 0.f, 0.f, 0.f};

  const uint4* wp_lane = Wp + lane;
  int bbase = brow << 9;
  int bxor = (brow & 7) << 4;

  for (int ks = 0; ks < 8; ++ks) {
    int koff = ks * 64 + q16;
    uint4 bv = *(const uint4*)((const char*)lds + bbase + (koff ^ bxor));
    bf16x8 bfrag = __builtin_bit_cast(bf16x8, bv);
#pragma unroll
    for (int mt = 0; mt < 8; ++mt) {
      uint4 av = wp_lane[(ks * 8 + mt) * 64];
      bf16x8 afrag = __builtin_bit_cast(bf16x8, av);
      acc[mt] = __builtin_amdgcn_mfma_f32_16x16x32_bf16(afrag, bfrag, acc[mt], 0, 0, 0);
    }
  }

  int orow = row0 + brow;
  if (orow < nrows) {
    unsigned short* op = out + (size_t)orow * 128;
#pragma unroll
    for (int mt = 0; mt < 8; ++mt) {
      int f0 = mt * 16 + q * 4;
      unsigned b01 = *(const unsigned*)(bias + f0);
      unsigned b23 = *(const unsigned*)(bias + f0 + 2);
      float v0 = fmaxf(acc[mt][0] + bflo(b01), 0.f);
      float v1 = fmaxf(acc[mt][1] + bfhi(b01), 0.f);
      float v2 = fmaxf(acc[mt][2] + bflo(b23), 0.f);
      float v3 = fmaxf(acc[mt][3] + bfhi(b23), 0.f);
      uint2 pk;
      pk.x = (unsigned)f2bf(v0) | ((unsigned)f2bf(v1) << 16);
      pk.y = (unsigned)f2bf(v2) | ((unsigned)f2bf(v3) << 16);
      *(uint2*)(op + f0) = pk;
    }
  }
}

// ============ plain MFMA conv (lin layers): out = [A|X]@[Wl;Wr] + b, relu ====
__global__ __launch_bounds__(256) void conv_mfma(
    const unsigned short* __restrict__ Abuf, const unsigned short* __restrict__ Xbuf,
    const uint4* __restrict__ Wp, const unsigned short* __restrict__ bias,
    unsigned short* __restrict__ out, int nrows) {
  __shared__ uint4 lds[2048];
  int tid = threadIdx.x;
  int row0 = blockIdx.x * 64;

  const char* Ab = (const char*)Abuf;
  const char* Xb = (const char*)Xbuf;
  for (int c = tid; c < 2048; c += 256) {
    int r = c >> 5, seg = c & 31;
    int gr = row0 + r;
    uint4 v = make_uint4(0u, 0u, 0u, 0u);
    if (gr < nrows) {
      const char* srcp = (seg < 16) ? (Ab + (size_t)gr * 256 + seg * 16)
                                    : (Xb + (size_t)gr * 256 + (seg - 16) * 16);
      v = *(const uint4*)srcp;
    }
    int byteoff = (r << 9) + ((seg << 4) ^ ((r & 7) << 4));
    *(uint4*)((char*)lds + byteoff) = v;
  }
  __syncthreads();

  int lane = tid & 63, w = tid >> 6;
  int brow = 16 * w + (lane & 15);
  int q = lane >> 4;
  int q16 = q << 4;

  f32x4 acc[8];
#pragma unroll
  for (int mt = 0; mt < 8; ++mt) acc[mt] = (f32x4){0.f, 0.f, 0.f, 0.f};

  const uint4* wp_lane = Wp + lane;
  int bbase = brow << 9;
  int bxor = (brow & 7) << 4;

  for (int ks = 0; ks < 8; ++ks) {
    int koff = ks * 64 + q16;
    uint4 bv = *(const uint4*)((const char*)lds + bbase + (koff ^ bxor));
    bf16x8 bfrag = __builtin_bit_cast(bf16x8, bv);
#pragma unroll
    for (int mt = 0; mt < 8; ++mt) {
      uint4 av = wp_lane[(ks * 8 + mt) * 64];
      bf16x8 afrag = __builtin_bit_cast(bf16x8, av);
      acc[mt] = __builtin_amdgcn_mfma_f32_16x16x32_bf16(afrag, bfrag, acc[mt], 0, 0, 0);
    }
  }

  int orow = row0 + brow;
  if (orow < nrows) {
    unsigned short* op = out + (size_t)orow * 128;
#pragma unroll
    for (int mt = 0; mt < 8; ++mt) {
      int f0 = mt * 16 + q * 4;
      unsigned b01 = *(const unsigned*)(bias + f0);
      unsigned b23 = *(const unsigned*)(bias + f0 + 2);
      float v0 = fmaxf(acc[mt][0] + bflo(b01), 0.f);
      float v1 = fmaxf(acc[mt][1] + bfhi(b01), 0.f);
      float v2 = fmaxf(acc[mt][2] + bflo(b23), 0.f);
      float v3 = fmaxf(acc[mt][3] + bfhi(b23), 0.f);
      uint2 pk;
      pk.x = (unsigned)f2bf(v0) | ((unsigned)f2bf(v1) << 16);
      pk.y = (unsigned)f2bf(v2) | ((unsigned)f2bf(v3) << 16);
      *(uint2*)(op + f0) = pk;
    }
  }
}

// ============ fused batch mean pool + head (per-graph block) ============
__global__ __launch_bounds__(512) void pool_head(
    const unsigned* __restrict__ hc2, const int* __restrict__ batch_c,
    const unsigned short* __restrict__ WB, void* __restrict__ out,
    const int* __restrict__ flag, int nC) {
  int b = blockIdx.x;
  int tid = threadIdx.x, lane = tid & 63, wv = tid >> 6;

  int lo = 0, hi = nC;
  while (lo < hi) { int m = (lo + hi) >> 1; if (batch_c[m] < b) lo = m + 1; else hi = m; }
  int st = lo;
  hi = nC;
  while (lo < hi) { int m = (lo + hi) >> 1; if (batch_c[m] < b + 1) lo = m + 1; else hi = m; }
  int en = lo;

  float ax = 0.f, ay = 0.f;
  int r = st + wv;
  for (; r + 24 < en; r += 32) {
    unsigned u0 = hc2[((size_t)(r)      << 6) + lane];
    unsigned u1 = hc2[((size_t)(r + 8)  << 6) + lane];
    unsigned u2 = hc2[((size_t)(r + 16) << 6) + lane];
    unsigned u3 = hc2[((size_t)(r + 24) << 6) + lane];
    ax += bflo(u0) + bflo(u1) + bflo(u2) + bflo(u3);
    ay += bfhi(u0) + bfhi(u1) + bfhi(u2) + bfhi(u3);
  }
  for (; r < en; r += 8) {
    unsigned u = hc2[((size_t)r << 6) + lane];
    ax += bflo(u); ay += bfhi(u);
  }

  __shared__ float sg[8][128];
  sg[wv][2 * lane]     = ax;
  sg[wv][2 * lane + 1] = ay;
  __syncthreads();

  __shared__ float gf[128];
  if (tid < 128) {
    float s = 0.f;
#pragma unroll
    for (int i = 0; i < 8; ++i) s += sg[i][tid];
    float sc = (en > st) ? 1.0f / (float)(en - st) : 0.f;
    gf[tid] = s * sc;
  }
  __syncthreads();

  __shared__ float lg[12];
  __shared__ float lse_s;
  if (tid < NCLS) {
    const unsigned short* W    = WB + 768;
    const unsigned short* bias = WB + 2048;
    float acc = bflo((unsigned)bias[tid]);
    for (int k = 0; k < 128; ++k)
      acc += gf[k] * bflo((unsigned)W[k * NCLS + tid]);
    lg[tid] = acc;
  }
  __syncthreads();
  if (tid == 0) {
    float m = lg[0];
    for (int c = 1; c < NCLS; ++c) m = fmaxf(m, lg[c]);
    float se = 0.f;
    for (int c = 0; c < NCLS; ++c) se += expf(lg[c] - m);
    lse_s = logf(se) + m;
  }
  __syncthreads();
  if (tid < NCLS) {
    float o = lg[tid] - lse_s;
    if (*flag) ((unsigned short*)out)[b * NCLS + tid] = f2bf(o);
    else       ((float*)out)[b * NCLS + tid] = o;
  }
}

extern "C" void kernel_launch(void* const* d_in, const int* in_sizes, int n_in,
                              void* d_out, int out_size, void* d_ws, size_t ws_size,
                              hipStream_t stream) {
  (void)in_sizes; (void)n_in; (void)out_size; (void)ws_size;
  const void* x        = d_in[0];
  const int*  ei       = (const int*)d_in[1];
  const int*  src      = ei;
  const int*  dst      = ei + N_EDGES;
  const int*  ci       = (const int*)d_in[3];
  const int*  cn       = ci;
  const int*  cc       = ci + N_MEMB;
  const int*  eip      = (const int*)d_in[4];
  const int*  srcp     = eip;
  const int*  dstp     = eip + N_EDGESP;
  const int*  batch_c  = (const int*)d_in[5];

  PackArgs pa;
  pa.wl[0] = d_in[8];  pa.wr[0] = d_in[10]; pa.wrOff[0] = 0;     pa.bb[0] = d_in[9];
  pa.wl[1] = d_in[11]; pa.wr[1] = d_in[13]; pa.wrOff[1] = 0;     pa.bb[1] = d_in[12];
  pa.wl[2] = d_in[14]; pa.wr[2] = d_in[14]; pa.wrOff[2] = 16384; pa.bb[2] = d_in[15];
  pa.wl[3] = d_in[16]; pa.wr[3] = d_in[18]; pa.wrOff[3] = 0;     pa.bb[3] = d_in[17];
  pa.wl[4] = d_in[19]; pa.wr[4] = d_in[21]; pa.wrOff[4] = 0;     pa.bb[4] = d_in[20];
  pa.wl[5] = d_in[22]; pa.wr[5] = d_in[22]; pa.wrOff[5] = 16384; pa.bb[5] = d_in[23];
  pa.w2 = d_in[6]; pa.b2 = d_in[7];

  char* base = (char*)d_ws;
  unsigned short* A0 = (unsigned short*)(base + OFF_A0);
  unsigned short* A1 = (unsigned short*)(base + OFF_A1);
  unsigned short* A2 = (unsigned short*)(base + OFF_A2);
  unsigned short* xB = (unsigned short*)(base + OFF_XB);
  uint4* wp0 = (uint4*)(base + OFF_WP);
  unsigned short* WBp = (unsigned short*)(base + OFF_WB);
  int*   ib  = (int*)(base + OFF_IB);
  unsigned* part = (unsigned*)(ib + I_PART);
  int* colA = ib + I_COL;
  int* nrp  = ib + I_NRP;
  int* mrp  = ib + I_MRP;
  int* crp  = ib + I_CRP;
  int* bcnt = ib + I_BCNT;
  int* pst  = ib + I_PST;
  int* bcur = ib + I_BCUR;
  int* flag = ib + I_FLAG;

#define WPK(L) (wp0 + (L) * 4096)

  probe_dtype<<<1, 64, 0, stream>>>((const unsigned short*)x, flag);

  // ---- ingestion (x -> bf16, weight packs, biases) ----
  ingest_all<<<6347, 256, 0, stream>>>(x, (uint4*)xB, pa, wp0, WBp, flag);

  // ---- fused CSR build (all 3 graphs) ----
  hipMemsetAsync(bcnt, 0, 544 * 4, stream);
  int nblk = (NETOT + PART_BLOCK - 1) / PART_BLOCK;       // 623
  bucket_count_all<<<nblk, 512, 0, stream>>>(src, dst, cn, cc, srcp, dstp, bcnt);
  scan_all<<<1, 512, 0, stream>>>(bcnt, pst, bcur);
  partition_all<<<nblk, 512, 0, stream>>>(src, dst, cn, cc, srcp, dstp, bcur, part);
  binned_fill_all<<<NBK_N + NBK_M + NBK_C, 1024, 0, stream>>>(part, pst, nrp, mrp, crp, colA);

  int gN = (N_NODES + 63) / 64, gC = (N_CLUST + 63) / 64;

  // ---- node block (gather fused into conv) ----
  gconv_mfma<<<gN, 256, 0, stream>>>(xB, nrp, colA, WPK(0), WBp + 0,   A1, N_NODES);
  gconv_mfma<<<gN, 256, 0, stream>>>(A1, nrp, colA, WPK(1), WBp + 128, A2, N_NODES);
  conv_mfma<<<gN, 256, 0, stream>>>(A1, A2, WPK(2), WBp + 256, A0, N_NODES);     // h -> A0

  // ---- cover pool: h -> hc (A1) ----
  gather_mean_bf16<<<N_CLUST / 4, 256, 0, stream>>>((const uint2*)A0, mrp, colA, (uint2*)A1, N_CLUST);

  // ---- cluster block ----
  gconv_mfma<<<gC, 256, 0, stream>>>(A1, crp, colA, WPK(3), WBp + 384, A2, N_CLUST);  // xc1 -> A2
  gconv_mfma<<<gC, 256, 0, stream>>>(A2, crp, colA, WPK(4), WBp + 512, A0, N_CLUST);  // xc2 -> A0
  conv_mfma<<<gC, 256, 0, stream>>>(A2, A0, WPK(5), WBp + 640, A1, N_CLUST);          // hc2 -> A1

  // ---- fused global mean pool + head ----
  pool_head<<<NB, 512, 0, stream>>>((const unsigned*)A1, batch_c, WBp, d_out, flag, N_CLUST);
}

// Round 10
// 491.660 us; speedup vs baseline: 1.2756x; 1.2756x over previous
//
#include <hip/hip_runtime.h>
#include <hip/hip_bf16.h>

// ---- problem constants ----
#define N_NODES   100000
#define N_EDGES   1600000
#define N_MEMB    150000
#define N_CLUST   40000
#define N_EDGESP  800000
#define NB        64
#define NCLS      10
#define NETOT     2550000        // E + M + E2

typedef __attribute__((ext_vector_type(4))) float f32x4;
typedef __attribute__((ext_vector_type(8))) short bf16x8;

// ---- workspace layout (byte offsets) ----
#define OFF_A0   0ul            // bf16 activation arena 0 (100000x128)
#define OFF_A1   25600000ul     // arena 1
#define OFF_A2   51200000ul     // arena 2
#define OFF_XB   76800000ul     // converted-input arena (bf16)
#define OFF_WP   102400000ul    // packed weights: 6 x 65536 B
#define OFF_WB   102793216ul    // converted biases + head weights (bf16)
#define OFF_IB   102801408ul    // int region (16B aligned)
// int region offsets (ints)
#define I_PART  0               // packed edge partition buffer (uint x 2.55M)
#define I_COL   2560000         // unified col array (2.55M)
#define I_NRP   5110016         // node rowptr 100001
#define I_MRP   5210032         // memb rowptr 40001
#define I_CRP   5250048         // cluster rowptr 40001
#define I_BCNT  5290064         // 544
#define I_PST   5290608         // 545
#define I_BCUR  5291168         // 544
#define I_FLAG  5291712
// end ~5.29M ints => total ws ~124 MB

#define PART_BLOCK 4096         // virtual edges per partition block (512 thr x 8)
#define SG_SHIFT   14
// partition geometry: node nbuck=49 ng=7 -> [0,343); memb nbuck=20 ng=7 ->
// [343,483); cluster nbuck=20 ng=3 -> [483,543)
#define PB_N   0
#define PB_M   343
#define PB_C   483
#define NPART  543
#define NBK_N  49
#define NBK_M  20
#define NBK_C  20

__device__ __forceinline__ unsigned short f2bf(float f) {   // RNE round
  unsigned u = __float_as_uint(f);
  return (unsigned short)((u + 0x7FFFu + ((u >> 16) & 1u)) >> 16);
}
__device__ __forceinline__ float bflo(unsigned u) { return __uint_as_float(u << 16); }
__device__ __forceinline__ float bfhi(unsigned u) { return __uint_as_float(u & 0xFFFF0000u); }

// Detect whether "float" inputs are bf16 (flag=1) or f32 (flag=0).
__global__ void probe_dtype(const unsigned short* __restrict__ x, int* __restrict__ flag) {
  if (blockIdx.x != 0 || threadIdx.x != 0) return;
  int wild = 0;
  for (int i = 0; i < 1024; i += 2) {
    int e = (x[i] >> 7) & 0xFF;
    if (e > 0x85) wild++;
  }
  *flag = (wild < 8) ? 1 : 0;
}

// ============ merged ingestion: x conversion + weight packs + biases ============
struct PackArgs {
  const void* wl[6];
  const void* wr[6];
  int         wrOff[6];
  const void* bb[6];
  const void* w2;
  const void* b2;
};

__global__ __launch_bounds__(256) void ingest_all(
    const void* __restrict__ x, uint4* __restrict__ xB,
    PackArgs pa, uint4* __restrict__ wp, unsigned short* __restrict__ wb,
    const int* __restrict__ flag) {
  int isb = *flag;
  int bid = blockIdx.x;
  if (bid < 6250) {                            // cvt_x: 8 elems/thread
    int gid = bid * 256 + threadIdx.x;
    if (gid >= 1600000) return;
    if (isb) {
      xB[gid] = ((const uint4*)x)[gid];
    } else {
      const float4* xf = (const float4*)x;
      float4 a = xf[2 * gid], b = xf[2 * gid + 1];
      unsigned short v[8] __attribute__((aligned(16)));
      v[0] = f2bf(a.x); v[1] = f2bf(a.y); v[2] = f2bf(a.z); v[3] = f2bf(a.w);
      v[4] = f2bf(b.x); v[5] = f2bf(b.y); v[6] = f2bf(b.z); v[7] = f2bf(b.w);
      xB[gid] = *(const uint4*)v;
    }
  } else if (bid < 6346) {                     // weight pack, MFMA A-frag order
    int pb = bid - 6250;                       // 0..95
    int L = pb >> 4;
    const void* Wlv = pa.wl[L];
    const void* Wrv = pa.wr[L];
    int wrOff = pa.wrOff[L];
    int t = (pb & 15) * 256 + threadIdx.x;     // 0..4095
    int lane = t & 63, mt = (t >> 6) & 7, ks = t >> 9;
    int feat = mt * 16 + (lane & 15);
    int k0 = ks * 32 + (lane >> 4) * 8;
    unsigned short v[8] __attribute__((aligned(16)));
#pragma unroll
    for (int j = 0; j < 8; ++j) {
      int k = k0 + j;
      int idx = ((k < 128) ? k * 128 : (k - 128) * 128 + wrOff) + feat;
      const void* W = (k < 128) ? Wlv : Wrv;
      v[j] = isb ? ((const unsigned short*)W)[idx] : f2bf(((const float*)W)[idx]);
    }
    wp[L * 4096 + t] = *(const uint4*)v;
  } else {                                     // biases + head weights
    for (int gid = threadIdx.x; gid < 2058; gid += 256) {
      const void* src; int local;
      if (gid < 768) { int seg = gid >> 7; local = gid & 127; src = pa.bb[seg]; }
      else if (gid < 2048) { src = pa.w2; local = gid - 768; }
      else { src = pa.b2; local = gid - 2048; }
      wb[gid] = isb ? ((const unsigned short*)src)[local] : f2bf(((const float*)src)[local]);
    }
  }
}

// ============ fused binned CSR build over all 3 graphs ============
__device__ __forceinline__ void vedge(int i,
    const int* __restrict__ s1, const int* __restrict__ d1,
    const int* __restrict__ s2, const int* __restrict__ d2,
    const int* __restrict__ s3, const int* __restrict__ d3,
    int& s, int& d, int& pk) {
  if (i < N_EDGES)               { s = s1[i]; d = d1[i]; pk = PB_N + (d >> 11) * 7 + (s >> SG_SHIFT); }
  else if (i < N_EDGES + N_MEMB) { int j = i - N_EDGES; s = s2[j]; d = d2[j]; pk = PB_M + (d >> 11) * 7 + (s >> SG_SHIFT); }
  else                           { int j = i - N_EDGES - N_MEMB; s = s3[j]; d = d3[j]; pk = PB_C + (d >> 11) * 3 + (s >> SG_SHIFT); }
}

__global__ __launch_bounds__(512) void bucket_count_all(
    const int* __restrict__ s1, const int* __restrict__ d1,
    const int* __restrict__ s2, const int* __restrict__ d2,
    const int* __restrict__ s3, const int* __restrict__ d3,
    int* __restrict__ bcnt) {
  __shared__ int h[544];
  int tid = threadIdx.x;
  h[tid] = 0;
  if (tid < 32) h[512 + tid] = 0;
  __syncthreads();
  int base = blockIdx.x * PART_BLOCK + tid;
#pragma unroll
  for (int j = 0; j < 8; ++j) {
    int i = base + j * 512;
    if (i < NETOT) { int s, d, pk; vedge(i, s1, d1, s2, d2, s3, d3, s, d, pk); atomicAdd(&h[pk], 1); }
  }
  __syncthreads();
  if (h[tid]) atomicAdd(&bcnt[tid], h[tid]);
  if (tid < 31 && h[512 + tid]) atomicAdd(&bcnt[512 + tid], h[512 + tid]);
}

__global__ __launch_bounds__(512) void scan_all(const int* __restrict__ bcnt,
                                                int* __restrict__ pstart,
                                                int* __restrict__ bcur) {
  __shared__ int ws[8];
  int tid = threadIdx.x, lane = tid & 63, wv = tid >> 6;
  int v0 = (2 * tid < NPART) ? bcnt[2 * tid] : 0;
  int v1 = (2 * tid + 1 < NPART) ? bcnt[2 * tid + 1] : 0;
  int s = v0 + v1;
  int inc = s;
  for (int off = 1; off < 64; off <<= 1) {
    int u = __shfl_up(inc, off);
    if (lane >= off) inc += u;
  }
  if (lane == 63) ws[wv] = inc;
  __syncthreads();
  int woff = 0;
  for (int k = 0; k < wv; ++k) woff += ws[k];
  int e0 = woff + inc - s;
  if (2 * tid < NPART)     { pstart[2 * tid] = e0;          bcur[2 * tid] = e0; }
  if (2 * tid + 1 < NPART) { pstart[2 * tid + 1] = e0 + v0; bcur[2 * tid + 1] = e0 + v0; }
  if (tid == 0) {
    int t = 0;
    for (int k = 0; k < 8; ++k) t += ws[k];
    pstart[NPART] = t;
  }
}

__global__ __launch_bounds__(512) void partition_all(
    const int* __restrict__ s1, const int* __restrict__ d1,
    const int* __restrict__ s2, const int* __restrict__ d2,
    const int* __restrict__ s3, const int* __restrict__ d3,
    int* __restrict__ bcur, unsigned* __restrict__ part) {
  __shared__ int h[544], lcur[544];
  int tid = threadIdx.x;
  h[tid] = 0;
  if (tid < 32) h[512 + tid] = 0;
  __syncthreads();
  int base = blockIdx.x * PART_BLOCK + tid;
  int s[8], d[8], bk[8];
#pragma unroll
  for (int j = 0; j < 8; ++j) {
    int i = base + j * 512;
    if (i < NETOT) { vedge(i, s1, d1, s2, d2, s3, d3, s[j], d[j], bk[j]); atomicAdd(&h[bk[j]], 1); }
    else bk[j] = -1;
  }
  __syncthreads();
  if (h[tid]) lcur[tid] = atomicAdd(&bcur[tid], h[tid]);
  if (tid < 31 && h[512 + tid]) lcur[512 + tid] = atomicAdd(&bcur[512 + tid], h[512 + tid]);
  __syncthreads();
#pragma unroll
  for (int j = 0; j < 8; ++j) {
    if (bk[j] >= 0) {
      int p = atomicAdd(&lcur[bk[j]], 1);
      part[p] = (unsigned)s[j] | ((unsigned)(d[j] & 2047) << 17);
    }
  }
}

__global__ __launch_bounds__(1024) void binned_fill_all(
    const unsigned* __restrict__ part, const int* __restrict__ pstart,
    int* __restrict__ nrp, int* __restrict__ mrp, int* __restrict__ crp,
    int* __restrict__ col) {
  __shared__ int cnt[2048];
  __shared__ int wsum[16];
  int b = blockIdx.x, tid = threadIdx.x;
  int buck, pb, ng, n;
  int* rp;
  if (b < NBK_N)               { buck = b;           pb = PB_N + buck * 7; ng = 7; rp = nrp; n = N_NODES; }
  else if (b < NBK_N + NBK_M)  { buck = b - NBK_N;   pb = PB_M + buck * 7; ng = 7; rp = mrp; n = N_CLUST; }
  else                         { buck = b - NBK_N - NBK_M; pb = PB_C + buck * 3; ng = 3; rp = crp; n = N_CLUST; }
  int nbase = buck << 11;
  int nn = n - nbase; if (nn > 2048) nn = 2048;
  cnt[tid] = 0; cnt[tid + 1024] = 0;
  __syncthreads();
  int e0 = pstart[pb], e1 = pstart[pb + ng];
  for (int e = e0 + tid; e < e1; e += 1024)
    atomicAdd(&cnt[part[e] >> 17], 1);
  __syncthreads();
  int c0 = cnt[2 * tid], c1 = cnt[2 * tid + 1];
  int s = c0 + c1;
  int lane = tid & 63, wv = tid >> 6;
  int inc = s;
  for (int off = 1; off < 64; off <<= 1) {
    int u = __shfl_up(inc, off);
    if (lane >= off) inc += u;
  }
  if (lane == 63) wsum[wv] = inc;
  __syncthreads();
  int woff = 0;
  for (int k = 0; k < wv; ++k) woff += wsum[k];
  int excl = woff + (inc - s);
  int r0 = e0 + excl;
  int r1 = r0 + c0;
  __syncthreads();
  cnt[2 * tid] = r0; cnt[2 * tid + 1] = r1;
  if (2 * tid < nn)     rp[nbase + 2 * tid]     = r0;
  if (2 * tid + 1 < nn) rp[nbase + 2 * tid + 1] = r1;
  __syncthreads();
  for (int g = 0; g < ng; ++g) {
    int f0 = pstart[pb + g], f1 = pstart[pb + g + 1];
    for (int e = f0 + tid; e < f1; e += 1024) {
      unsigned ed = part[e];
      int p = atomicAdd(&cnt[ed >> 17], 1);
      col[p] = (int)(ed & 0x1FFFFu);
    }
    __syncthreads();
  }
  if (tid == 0) {
    if (b == NBK_N - 1)                 nrp[N_NODES] = pstart[PB_M];
    if (b == NBK_N + NBK_M - 1)         mrp[N_CLUST] = pstart[PB_C];
    if (b == NBK_N + NBK_M + NBK_C - 1) crp[N_CLUST] = pstart[NPART];
  }
}

// ============ pull-mode mean aggregation, bf16 rows (256 B) ============
// one wave per dst row; half-wave per edge; lane owns 4 features (uint2);
// 8-deep unroll => 16 edges in flight per wave. (Proven 72.8 us @ node graph
// = LLC-service floor; do not fuse with conv — r9 showed -50% throughput.)
__global__ __launch_bounds__(256) void gather_mean_bf16(
    const uint2* __restrict__ x, const int* __restrict__ rowptr, const int* __restrict__ col,
    uint2* __restrict__ out, int n) {
  int w = (blockIdx.x * 256 + threadIdx.x) >> 6;
  if (w >= n) return;
  int lane = threadIdx.x & 63;
  int half = lane >> 5, p = lane & 31;
  int s0 = rowptr[w], s1 = rowptr[w + 1];
  float a0 = 0.f, a1 = 0.f, a2 = 0.f, a3 = 0.f;
  int j = s0 + half;
  for (; j + 14 < s1; j += 16) {
    uint2 v[8];
#pragma unroll
    for (int u = 0; u < 8; ++u) v[u] = x[((size_t)col[j + 2 * u] << 5) + p];
#pragma unroll
    for (int u = 0; u < 8; ++u) {
      a0 += bflo(v[u].x); a1 += bfhi(v[u].x);
      a2 += bflo(v[u].y); a3 += bfhi(v[u].y);
    }
  }
  for (; j < s1; j += 2) {
    uint2 v = x[((size_t)col[j] << 5) + p];
    a0 += bflo(v.x); a1 += bfhi(v.x);
    a2 += bflo(v.y); a3 += bfhi(v.y);
  }
  a0 += __shfl_xor(a0, 32); a1 += __shfl_xor(a1, 32);
  a2 += __shfl_xor(a2, 32); a3 += __shfl_xor(a3, 32);
  if (half == 0) {
    float sc = (s1 > s0) ? 1.0f / (float)(s1 - s0) : 0.f;
    uint2 r;
    r.x = (unsigned)f2bf(a0 * sc) | ((unsigned)f2bf(a1 * sc) << 16);
    r.y = (unsigned)f2bf(a2 * sc) | ((unsigned)f2bf(a3 * sc) << 16);
    out[((size_t)w << 5) + p] = r;
  }
}

// ============ MFMA conv: out = relu([A|X] @ [Wl;Wr] + b), K=256 ============
__global__ __launch_bounds__(256) void conv_mfma(
    const unsigned short* __restrict__ Abuf, const unsigned short* __restrict__ Xbuf,
    const uint4* __restrict__ Wp, const unsigned short* __restrict__ bias,
    unsigned short* __restrict__ out, int nrows) {
  __shared__ uint4 lds[2048];                  // 32 KB
  int tid = threadIdx.x;
  int row0 = blockIdx.x * 64;

  const char* Ab = (const char*)Abuf;
  const char* Xb = (const char*)Xbuf;
  for (int c = tid; c < 2048; c += 256) {
    int r = c >> 5, seg = c & 31;
    int gr = row0 + r;
    uint4 v = make_uint4(0u, 0u, 0u, 0u);
    if (gr < nrows) {
      const char* srcp = (seg < 16) ? (Ab + (size_t)gr * 256 + seg * 16)
                                    : (Xb + (size_t)gr * 256 + (seg - 16) * 16);
      v = *(const uint4*)srcp;
    }
    int byteoff = (r << 9) + ((seg << 4) ^ ((r & 7) << 4));
    *(uint4*)((char*)lds + byteoff) = v;
  }
  __syncthreads();

  int lane = tid & 63, w = tid >> 6;
  int brow = 16 * w + (lane & 15);
  int q = lane >> 4;
  int q16 = q << 4;

  f32x4 acc[8];
#pragma unroll
  for (int mt = 0; mt < 8; ++mt) acc[mt] = (f32x4){0.f, 0.f, 0.f, 0.f};

  const uint4* wp_lane = Wp + lane;
  int bbase = brow << 9;
  int bxor = (brow & 7) << 4;

  for (int ks = 0; ks < 8; ++ks) {
    int koff = ks * 64 + q16;
    uint4 bv = *(const uint4*)((const char*)lds + bbase + (koff ^ bxor));
    bf16x8 bfrag = __builtin_bit_cast(bf16x8, bv);
#pragma unroll
    for (int mt = 0; mt < 8; ++mt) {
      uint4 av = wp_lane[(ks * 8 + mt) * 64];
      bf16x8 afrag = __builtin_bit_cast(bf16x8, av);
      acc[mt] = __builtin_amdgcn_mfma_f32_16x16x32_bf16(afrag, bfrag, acc[mt], 0, 0, 0);
    }
  }

  int orow = row0 + brow;
  if (orow < nrows) {
    unsigned short* op = out + (size_t)orow * 128;
#pragma unroll
    for (int mt = 0; mt < 8; ++mt) {
      int f0 = mt * 16 + q * 4;
      unsigned b01 = *(const unsigned*)(bias + f0);
      unsigned b23 = *(const unsigned*)(bias + f0 + 2);
      float v0 = fmaxf(acc[mt][0] + bflo(b01), 0.f);
      float v1 = fmaxf(acc[mt][1] + bfhi(b01), 0.f);
      float v2 = fmaxf(acc[mt][2] + bflo(b23), 0.f);
      float v3 = fmaxf(acc[mt][3] + bfhi(b23), 0.f);
      uint2 pk;
      pk.x = (unsigned)f2bf(v0) | ((unsigned)f2bf(v1) << 16);
      pk.y = (unsigned)f2bf(v2) | ((unsigned)f2bf(v3) << 16);
      *(uint2*)(op + f0) = pk;
    }
  }
}

// ============ fused batch mean pool + head (per-graph block) ============
__global__ __launch_bounds__(512) void pool_head(
    const unsigned* __restrict__ hc2, const int* __restrict__ batch_c,
    const unsigned short* __restrict__ WB, void* __restrict__ out,
    const int* __restrict__ flag, int nC) {
  int b = blockIdx.x;
  int tid = threadIdx.x, lane = tid & 63, wv = tid >> 6;

  int lo = 0, hi = nC;
  while (lo < hi) { int m = (lo + hi) >> 1; if (batch_c[m] < b) lo = m + 1; else hi = m; }
  int st = lo;
  hi = nC;
  while (lo < hi) { int m = (lo + hi) >> 1; if (batch_c[m] < b + 1) lo = m + 1; else hi = m; }
  int en = lo;

  float ax = 0.f, ay = 0.f;
  int r = st + wv;
  for (; r + 24 < en; r += 32) {
    unsigned u0 = hc2[((size_t)(r)      << 6) + lane];
    unsigned u1 = hc2[((size_t)(r + 8)  << 6) + lane];
    unsigned u2 = hc2[((size_t)(r + 16) << 6) + lane];
    unsigned u3 = hc2[((size_t)(r + 24) << 6) + lane];
    ax += bflo(u0) + bflo(u1) + bflo(u2) + bflo(u3);
    ay += bfhi(u0) + bfhi(u1) + bfhi(u2) + bfhi(u3);
  }
  for (; r < en; r += 8) {
    unsigned u = hc2[((size_t)r << 6) + lane];
    ax += bflo(u); ay += bfhi(u);
  }

  __shared__ float sg[8][128];
  sg[wv][2 * lane]     = ax;
  sg[wv][2 * lane + 1] = ay;
  __syncthreads();

  __shared__ float gf[128];
  if (tid < 128) {
    float s = 0.f;
#pragma unroll
    for (int i = 0; i < 8; ++i) s += sg[i][tid];
    float sc = (en > st) ? 1.0f / (float)(en - st) : 0.f;
    gf[tid] = s * sc;
  }
  __syncthreads();

  __shared__ float lg[12];
  __shared__ float lse_s;
  if (tid < NCLS) {
    const unsigned short* W    = WB + 768;
    const unsigned short* bias = WB + 2048;
    float acc = bflo((unsigned)bias[tid]);
    for (int k = 0; k < 128; ++k)
      acc += gf[k] * bflo((unsigned)W[k * NCLS + tid]);
    lg[tid] = acc;
  }
  __syncthreads();
  if (tid == 0) {
    float m = lg[0];
    for (int c = 1; c < NCLS; ++c) m = fmaxf(m, lg[c]);
    float se = 0.f;
    for (int c = 0; c < NCLS; ++c) se += expf(lg[c] - m);
    lse_s = logf(se) + m;
  }
  __syncthreads();
  if (tid < NCLS) {
    float o = lg[tid] - lse_s;
    if (*flag) ((unsigned short*)out)[b * NCLS + tid] = f2bf(o);
    else       ((float*)out)[b * NCLS + tid] = o;
  }
}

extern "C" void kernel_launch(void* const* d_in, const int* in_sizes, int n_in,
                              void* d_out, int out_size, void* d_ws, size_t ws_size,
                              hipStream_t stream) {
  (void)in_sizes; (void)n_in; (void)out_size; (void)ws_size;
  const void* x        = d_in[0];
  const int*  ei       = (const int*)d_in[1];
  const int*  src      = ei;
  const int*  dst      = ei + N_EDGES;
  const int*  ci       = (const int*)d_in[3];
  const int*  cn       = ci;
  const int*  cc       = ci + N_MEMB;
  const int*  eip      = (const int*)d_in[4];
  const int*  srcp     = eip;
  const int*  dstp     = eip + N_EDGESP;
  const int*  batch_c  = (const int*)d_in[5];

  PackArgs pa;
  pa.wl[0] = d_in[8];  pa.wr[0] = d_in[10]; pa.wrOff[0] = 0;     pa.bb[0] = d_in[9];
  pa.wl[1] = d_in[11]; pa.wr[1] = d_in[13]; pa.wrOff[1] = 0;     pa.bb[1] = d_in[12];
  pa.wl[2] = d_in[14]; pa.wr[2] = d_in[14]; pa.wrOff[2] = 16384; pa.bb[2] = d_in[15];
  pa.wl[3] = d_in[16]; pa.wr[3] = d_in[18]; pa.wrOff[3] = 0;     pa.bb[3] = d_in[17];
  pa.wl[4] = d_in[19]; pa.wr[4] = d_in[21]; pa.wrOff[4] = 0;     pa.bb[4] = d_in[20];
  pa.wl[5] = d_in[22]; pa.wr[5] = d_in[22]; pa.wrOff[5] = 16384; pa.bb[5] = d_in[23];
  pa.w2 = d_in[6]; pa.b2 = d_in[7];

  char* base = (char*)d_ws;
  unsigned short* A0 = (unsigned short*)(base + OFF_A0);
  unsigned short* A1 = (unsigned short*)(base + OFF_A1);
  unsigned short* A2 = (unsigned short*)(base + OFF_A2);
  unsigned short* xB = (unsigned short*)(base + OFF_XB);
  uint4* wp0 = (uint4*)(base + OFF_WP);
  unsigned short* WBp = (unsigned short*)(base + OFF_WB);
  int*   ib  = (int*)(base + OFF_IB);
  unsigned* part = (unsigned*)(ib + I_PART);
  int* colA = ib + I_COL;
  int* nrp  = ib + I_NRP;
  int* mrp  = ib + I_MRP;
  int* crp  = ib + I_CRP;
  int* bcnt = ib + I_BCNT;
  int* pst  = ib + I_PST;
  int* bcur = ib + I_BCUR;
  int* flag = ib + I_FLAG;

#define WPK(L) (wp0 + (L) * 4096)

  probe_dtype<<<1, 64, 0, stream>>>((const unsigned short*)x, flag);

  // ---- ingestion (x -> bf16, weight packs, biases) ----
  ingest_all<<<6347, 256, 0, stream>>>(x, (uint4*)xB, pa, wp0, WBp, flag);

  // ---- fused CSR build (all 3 graphs) ----
  hipMemsetAsync(bcnt, 0, 544 * 4, stream);
  int nblk = (NETOT + PART_BLOCK - 1) / PART_BLOCK;       // 623
  bucket_count_all<<<nblk, 512, 0, stream>>>(src, dst, cn, cc, srcp, dstp, bcnt);
  scan_all<<<1, 512, 0, stream>>>(bcnt, pst, bcur);
  partition_all<<<nblk, 512, 0, stream>>>(src, dst, cn, cc, srcp, dstp, bcur, part);
  binned_fill_all<<<NBK_N + NBK_M + NBK_C, 1024, 0, stream>>>(part, pst, nrp, mrp, crp, colA);

  int gN = (N_NODES + 63) / 64, gC = (N_CLUST + 63) / 64;

  // ---- node block (separate gather + conv: r9 proved fusion loses) ----
  gather_mean_bf16<<<N_NODES / 4, 256, 0, stream>>>((const uint2*)xB, nrp, colA, (uint2*)A0, N_NODES);
  conv_mfma<<<gN, 256, 0, stream>>>(A0, xB, WPK(0), WBp + 0,   A1, N_NODES);
  gather_mean_bf16<<<N_NODES / 4, 256, 0, stream>>>((const uint2*)A1, nrp, colA, (uint2*)A0, N_NODES);
  conv_mfma<<<gN, 256, 0, stream>>>(A0, A1, WPK(1), WBp + 128, A2, N_NODES);
  conv_mfma<<<gN, 256, 0, stream>>>(A1, A2, WPK(2), WBp + 256, A0, N_NODES);     // h -> A0

  // ---- cover pool: h -> hc (A1) ----
  gather_mean_bf16<<<N_CLUST / 4, 256, 0, stream>>>((const uint2*)A0, mrp, colA, (uint2*)A1, N_CLUST);

  // ---- cluster block ----
  gather_mean_bf16<<<N_CLUST / 4, 256, 0, stream>>>((const uint2*)A1, crp, colA, (uint2*)A2, N_CLUST);
  conv_mfma<<<gC, 256, 0, stream>>>(A2, A1, WPK(3), WBp + 384, A0, N_CLUST);     // xc1 -> A0
  gather_mean_bf16<<<N_CLUST / 4, 256, 0, stream>>>((const uint2*)A0, crp, colA, (uint2*)A2, N_CLUST);
  conv_mfma<<<gC, 256, 0, stream>>>(A2, A0, WPK(4), WBp + 512, A1, N_CLUST);     // xc2 -> A1
  conv_mfma<<<gC, 256, 0, stream>>>(A0, A1, WPK(5), WBp + 640, A2, N_CLUST);     // hc2 -> A2

  // ---- fused global mean pool + head ----
  pool_head<<<NB, 512, 0, stream>>>((const unsigned*)A2, batch_c, WBp, d_out, flag, N_CLUST);
}